// Round 1
// baseline (645.640 us; speedup 1.0000x reference)
//
#include <hip/hip_runtime.h>
#include <math.h>

typedef short bf16x8 __attribute__((ext_vector_type(8)));
typedef float f32x4 __attribute__((ext_vector_type(4)));

#define QKSCALE 0.17677669529663687f  // 32^-0.5

__device__ __forceinline__ unsigned short f2bf(float f) {
  unsigned int u = __float_as_uint(f);
  u = (u + 0x7FFFu + ((u >> 16) & 1u)) >> 16;
  return (unsigned short)u;
}
__device__ __forceinline__ float bf2f(unsigned short h) {
  return __uint_as_float(((unsigned int)h) << 16);
}

// XOR-swizzled LDS helpers: row-major [rows][strideHalfs] bf16 tiles.
__device__ __forceinline__ bf16x8 ldsv(const unsigned short* base, int row, int strideHalfs, int kHalf, int swzMask) {
  int byte = row * strideHalfs * 2 + kHalf * 2;
  byte ^= (row & swzMask) << 4;
  return *(const bf16x8*)((const char*)base + byte);
}
__device__ __forceinline__ void ldss(unsigned short* base, int row, int strideHalfs, int col, int swzMask, unsigned short v) {
  int byte = row * strideHalfs * 2 + col * 2;
  byte ^= (row & swzMask) << 4;
  *(unsigned short*)((char*)base + byte) = v;
}
__device__ __forceinline__ unsigned short ldsl(const unsigned short* base, int row, int strideHalfs, int col, int swzMask) {
  int byte = row * strideHalfs * 2 + col * 2;
  byte ^= (row & swzMask) << 4;
  return *(const unsigned short*)((const char*)base + byte);
}

// ---------------- prep: bf16 weights (+SCALE folded into q rows) + bias matrix ----------------
__global__ void prep_kernel(
    const float* __restrict__ qkv1_w, const float* __restrict__ qkv1_b,
    const float* __restrict__ proj_w, const float* __restrict__ fc1_w,
    const float* __restrict__ fc2_w,  const float* __restrict__ rpb,
    unsigned short* __restrict__ Wqkv, unsigned short* __restrict__ Wproj,
    unsigned short* __restrict__ Wfc1, unsigned short* __restrict__ Wfc2,
    float* __restrict__ bqkv, float* __restrict__ biasmat)
{
  int i = blockIdx.x * 256 + threadIdx.x;
  if (i < 65536) {  // qkv1_w (512,128), comp = row>>7; scale q (0) and q2 (3)
    int row = i >> 7, comp = row >> 7;
    float sc = (comp == 0 || comp == 3) ? QKSCALE : 1.f;
    Wqkv[i] = f2bf(qkv1_w[i] * sc);
  }
  int j = i - 65536;
  if (j >= 0 && j < 16384) Wproj[j] = f2bf(proj_w[j]);
  j -= 16384;
  if (j >= 0 && j < 65536) Wfc1[j] = f2bf(fc1_w[j]);
  j -= 65536;
  if (j >= 0 && j < 65536) Wfc2[j] = f2bf(fc2_w[j]);
  j -= 65536;
  if (j >= 0 && j < 512) {
    int comp = j >> 7;
    bqkv[j] = qkv1_b[j] * ((comp == 0 || comp == 3) ? QKSCALE : 1.f);
  }
  j -= 512;
  if (j >= 0 && j < 16384) {  // biasmat[h][n][m]
    int hh = j >> 12, n = (j >> 6) & 63, m = j & 63;
    int di = (n >> 3) - (m >> 3) + 7, dj = (n & 7) - (m & 7) + 7;
    biasmat[j] = rpb[(di * 15 + dj) * 4 + hh];
  }
}

// ---------------- attention mega-kernel: 1 block = 1 window (both streams) ----------------
__global__ void __launch_bounds__(256) attn_kernel(
    const float* __restrict__ x_in, const float* __restrict__ d_in_,
    const float* __restrict__ n1w, const float* __restrict__ n1b,
    const unsigned short* __restrict__ Wqkv, const float* __restrict__ bqkv,
    const unsigned short* __restrict__ Wproj, const float* __restrict__ projb,
    const float* __restrict__ biasmat,
    float* __restrict__ out)
{
  __shared__ unsigned short xln[2][64 * 128];   // 32KB  LN'd tokens bf16 (swz mask 7)
  __shared__ unsigned short qk[2][4][64 * 32];  // 32KB  per-head q,k,v(T),q2 (mask 3 / v: mask 7)
  __shared__ unsigned short P[64 * 64];         // 8KB   combined softmax (mask 7)
  __shared__ unsigned short pvh[64 * 32];       // 4KB   PV output staging (mask 3)

  const int tid = threadIdx.x;
  const int wid = tid >> 6;
  const int lane = tid & 63;
  const int l4 = lane >> 4;
  const int l15 = lane & 15;

  const int win = blockIdx.x;
  const int b = win >> 8, hb = (win >> 4) & 15, wb = win & 15;
  const int base_row = b * 16384 + hb * 8 * 128 + wb * 8;
  // token t -> global row: base_row + (t>>3)*128 + (t&7)

  // ---- LN1 (both streams) ----
  {
    const int t = tid >> 2, q4 = tid & 3;
    const int grow = base_row + (t >> 3) * 128 + (t & 7);
    for (int s = 0; s < 2; ++s) {
      const float* src = (s ? d_in_ : x_in) + (size_t)grow * 128 + q4 * 32;
      float v[32];
      float sum = 0.f, ss = 0.f;
#pragma unroll
      for (int i = 0; i < 8; ++i) {
        float4 f = ((const float4*)src)[i];
        v[i * 4 + 0] = f.x; v[i * 4 + 1] = f.y; v[i * 4 + 2] = f.z; v[i * 4 + 3] = f.w;
        sum += f.x + f.y + f.z + f.w;
        ss += f.x * f.x + f.y * f.y + f.z * f.z + f.w * f.w;
      }
      sum += __shfl_xor(sum, 1); sum += __shfl_xor(sum, 2);
      ss  += __shfl_xor(ss, 1);  ss  += __shfl_xor(ss, 2);
      float mean = sum * (1.f / 128.f);
      float var = ss * (1.f / 128.f) - mean * mean;
      float rs = rsqrtf(var + 1e-5f);
#pragma unroll
      for (int i = 0; i < 32; ++i) {
        int c = q4 * 32 + i;
        float nv = (v[i] - mean) * rs * n1w[c] + n1b[c];
        ldss(xln[s], t, 128, c, 7, f2bf(nv));
      }
    }
  }

  const f32x4 fzero = {0.f, 0.f, 0.f, 0.f};
  f32x4 pacc[2][8];
#pragma unroll
  for (int s = 0; s < 2; ++s)
#pragma unroll
    for (int n = 0; n < 8; ++n) pacc[s][n] = fzero;

  const int role = wid & 1;  // row-half in score phase
  const int kind = wid >> 1; // 0: S_a (q0[s]*k[s] [+bias if s==0]); 1: S_b (q2[1-s]*k[s])

  for (int h = 0; h < 4; ++h) {
    __syncthreads();  // protect qkv LDS reuse (and xln after LN for h==0)
    // ---- QKV for head h: M = 16 rows/wave per stream, N=128 (4 comps x 32), K=128 ----
    {
      f32x4 acc[2][8];
#pragma unroll
      for (int s = 0; s < 2; ++s)
#pragma unroll
        for (int n = 0; n < 8; ++n) acc[s][n] = fzero;
#pragma unroll
      for (int kk = 0; kk < 4; ++kk) {
        const int kh = kk * 32 + l4 * 8;
        bf16x8 a0 = ldsv(xln[0], 16 * wid + l15, 128, kh, 7);
        bf16x8 a1 = ldsv(xln[1], 16 * wid + l15, 128, kh, 7);
#pragma unroll
        for (int nf = 0; nf < 8; ++nf) {
          const int nl = nf * 16 + l15;
          const int wrow = (nl >> 5) * 128 + h * 32 + (nl & 31);
          bf16x8 bb = *(const bf16x8*)(Wqkv + wrow * 128 + kh);
          acc[0][nf] = __builtin_amdgcn_mfma_f32_16x16x32_bf16(a0, bb, acc[0][nf], 0, 0, 0);
          acc[1][nf] = __builtin_amdgcn_mfma_f32_16x16x32_bf16(a1, bb, acc[1][nf], 0, 0, 0);
        }
      }
#pragma unroll
      for (int s = 0; s < 2; ++s)
#pragma unroll
        for (int nf = 0; nf < 8; ++nf) {
          const int nl = nf * 16 + l15;
          const int comp = nl >> 5, sub = nl & 31;
          const float bias = bqkv[comp * 128 + h * 32 + sub];
#pragma unroll
          for (int r = 0; r < 4; ++r) {
            const int tok = 16 * wid + l4 * 4 + r;
            unsigned short hv = f2bf(acc[s][nf][r] + bias);
            if (comp == 2) ldss(qk[s][2], sub, 64, tok, 7, hv);  // v stored transposed [32][64]
            else           ldss(qk[s][comp], tok, 32, sub, 3, hv);
          }
        }
    }
    __syncthreads();

    for (int s = 0; s < 2; ++s) {
      // ---- scores + in-register softmax ----
      float pn[2][4][4];  // [mf][nf][reg]
      {
        f32x4 acc[2][4];
#pragma unroll
        for (int mf = 0; mf < 2; ++mf)
#pragma unroll
          for (int nf = 0; nf < 4; ++nf) acc[mf][nf] = fzero;
        const unsigned short* Abuf = kind ? qk[1 - s][3] : qk[s][0];
        const unsigned short* Kbuf = qk[s][1];
        const int kh = l4 * 8;
#pragma unroll
        for (int mf = 0; mf < 2; ++mf) {
          bf16x8 a = ldsv(Abuf, role * 32 + mf * 16 + l15, 32, kh, 3);
#pragma unroll
          for (int nf = 0; nf < 4; ++nf) {
            bf16x8 bb = ldsv(Kbuf, nf * 16 + l15, 32, kh, 3);
            acc[mf][nf] = __builtin_amdgcn_mfma_f32_16x16x32_bf16(a, bb, acc[mf][nf], 0, 0, 0);
          }
        }
        if (s == 0 && kind == 0) {  // rel-pos bias only on the r-branch
#pragma unroll
          for (int mf = 0; mf < 2; ++mf)
#pragma unroll
            for (int nf = 0; nf < 4; ++nf)
#pragma unroll
              for (int r = 0; r < 4; ++r) {
                int row = role * 32 + mf * 16 + l4 * 4 + r;
                int col = nf * 16 + l15;
                acc[mf][nf][r] += biasmat[(h * 64 + row) * 64 + col];
              }
        }
#pragma unroll
        for (int mf = 0; mf < 2; ++mf)
#pragma unroll
          for (int r = 0; r < 4; ++r) {
            float v0 = acc[mf][0][r], v1 = acc[mf][1][r], v2 = acc[mf][2][r], v3 = acc[mf][3][r];
            float m = fmaxf(fmaxf(v0, v1), fmaxf(v2, v3));
            m = fmaxf(m, __shfl_xor(m, 1));
            m = fmaxf(m, __shfl_xor(m, 2));
            m = fmaxf(m, __shfl_xor(m, 4));
            m = fmaxf(m, __shfl_xor(m, 8));
            float e0 = __expf(v0 - m), e1 = __expf(v1 - m), e2 = __expf(v2 - m), e3 = __expf(v3 - m);
            float sm = e0 + e1 + e2 + e3;
            sm += __shfl_xor(sm, 1); sm += __shfl_xor(sm, 2);
            sm += __shfl_xor(sm, 4); sm += __shfl_xor(sm, 8);
            float inv = 1.f / sm;
            pn[mf][0][r] = e0 * inv; pn[mf][1][r] = e1 * inv;
            pn[mf][2][r] = e2 * inv; pn[mf][3][r] = e3 * inv;
          }
      }
      if (kind == 0) {
#pragma unroll
        for (int mf = 0; mf < 2; ++mf)
#pragma unroll
          for (int nf = 0; nf < 4; ++nf)
#pragma unroll
            for (int r = 0; r < 4; ++r) {
              int row = role * 32 + mf * 16 + l4 * 4 + r, col = nf * 16 + l15;
              ldss(P, row, 64, col, 7, f2bf(pn[mf][nf][r]));
            }
      }
      __syncthreads();
      if (kind == 1) {  // single-writer RMW add
#pragma unroll
        for (int mf = 0; mf < 2; ++mf)
#pragma unroll
          for (int nf = 0; nf < 4; ++nf)
#pragma unroll
            for (int r = 0; r < 4; ++r) {
              int row = role * 32 + mf * 16 + l4 * 4 + r, col = nf * 16 + l15;
              float cur = bf2f(ldsl(P, row, 64, col, 7));
              ldss(P, row, 64, col, 7, f2bf(cur + pn[mf][nf][r]));
            }
      }
      __syncthreads();
      // ---- PV: M=16 rows/wave, N=32, K=64 ----
      {
        f32x4 acc2[2];
        acc2[0] = fzero; acc2[1] = fzero;
#pragma unroll
        for (int kk = 0; kk < 2; ++kk) {
          const int kh = kk * 32 + l4 * 8;
          bf16x8 a = ldsv(P, 16 * wid + l15, 64, kh, 7);
#pragma unroll
          for (int nf = 0; nf < 2; ++nf) {
            bf16x8 bb = ldsv(qk[s][2], nf * 16 + l15, 64, kh, 7);
            acc2[nf] = __builtin_amdgcn_mfma_f32_16x16x32_bf16(a, bb, acc2[nf], 0, 0, 0);
          }
        }
#pragma unroll
        for (int nf = 0; nf < 2; ++nf)
#pragma unroll
          for (int r = 0; r < 4; ++r) {
            int tok = 16 * wid + l4 * 4 + r, hd = nf * 16 + l15;
            ldss(pvh, tok, 32, hd, 3, f2bf(acc2[nf][r]));
          }
      }
      __syncthreads();
      // ---- proj accumulate (K = this head's 32 channels) ----
      {
        const int kh = l4 * 8;
        bf16x8 a = ldsv(pvh, 16 * wid + l15, 32, kh, 3);
#pragma unroll
        for (int nf = 0; nf < 8; ++nf) {
          int n = nf * 16 + l15;
          bf16x8 bb = *(const bf16x8*)(Wproj + n * 128 + h * 32 + kh);
          pacc[s][nf] = __builtin_amdgcn_mfma_f32_16x16x32_bf16(a, bb, pacc[s][nf], 0, 0, 0);
        }
      }
    }
  }
  // ---- epilogue: + proj bias + residual, window-reverse write ----
#pragma unroll
  for (int s = 0; s < 2; ++s) {
    const float* resid = (s ? d_in_ : x_in);
    float* dst = out + (size_t)s * (4 * 16384 * 128);
#pragma unroll
    for (int nf = 0; nf < 8; ++nf) {
      int col = nf * 16 + l15;
#pragma unroll
      for (int r = 0; r < 4; ++r) {
        int tok = 16 * wid + l4 * 4 + r;
        int grow = base_row + (tok >> 3) * 128 + (tok & 7);
        size_t off = (size_t)grow * 128 + col;
        dst[off] = pacc[s][nf][r] + projb[col] + resid[off];
      }
    }
  }
}

// ---------------- MLP mega-kernel: 1 block = 64 tokens, in-place on out ----------------
__global__ void __launch_bounds__(256) mlp_kernel(
    const float* __restrict__ n2w, const float* __restrict__ n2b,
    const unsigned short* __restrict__ Wfc1, const float* __restrict__ fc1b,
    const unsigned short* __restrict__ Wfc2, const float* __restrict__ fc2b,
    float* __restrict__ out)
{
  __shared__ unsigned short xn[64 * 128];    // 16KB (mask 7)
  __shared__ unsigned short hbuf[64 * 512];  // 64KB (mask 7)
  const int tid = threadIdx.x, wid = tid >> 6, lane = tid & 63, l4 = lane >> 4, l15 = lane & 15;
  const size_t rbase = (size_t)blockIdx.x * 64;
  const f32x4 fzero = {0.f, 0.f, 0.f, 0.f};

  {
    const int t = tid >> 2, q4 = tid & 3;
    const float* src = out + (rbase + t) * 128 + q4 * 32;
    float v[32];
    float sum = 0.f, ss = 0.f;
#pragma unroll
    for (int i = 0; i < 8; ++i) {
      float4 f = ((const float4*)src)[i];
      v[i * 4 + 0] = f.x; v[i * 4 + 1] = f.y; v[i * 4 + 2] = f.z; v[i * 4 + 3] = f.w;
      sum += f.x + f.y + f.z + f.w;
      ss += f.x * f.x + f.y * f.y + f.z * f.z + f.w * f.w;
    }
    sum += __shfl_xor(sum, 1); sum += __shfl_xor(sum, 2);
    ss  += __shfl_xor(ss, 1);  ss  += __shfl_xor(ss, 2);
    float mean = sum * (1.f / 128.f), var = ss * (1.f / 128.f) - mean * mean;
    float rs = rsqrtf(var + 1e-5f);
#pragma unroll
    for (int i = 0; i < 32; ++i) {
      int c = q4 * 32 + i;
      ldss(xn, t, 128, c, 7, f2bf((v[i] - mean) * rs * n2w[c] + n2b[c]));
    }
  }
  __syncthreads();
  // fc1 + exact gelu
  for (int nc = 0; nc < 4; ++nc) {
    f32x4 acc[8];
#pragma unroll
    for (int nf = 0; nf < 8; ++nf) acc[nf] = fzero;
#pragma unroll
    for (int kk = 0; kk < 4; ++kk) {
      const int kh = kk * 32 + l4 * 8;
      bf16x8 a = ldsv(xn, 16 * wid + l15, 128, kh, 7);
#pragma unroll
      for (int nf = 0; nf < 8; ++nf) {
        int n = nc * 128 + nf * 16 + l15;
        bf16x8 bb = *(const bf16x8*)(Wfc1 + n * 128 + kh);
        acc[nf] = __builtin_amdgcn_mfma_f32_16x16x32_bf16(a, bb, acc[nf], 0, 0, 0);
      }
    }
#pragma unroll
    for (int nf = 0; nf < 8; ++nf) {
      int n = nc * 128 + nf * 16 + l15;
      float bias = fc1b[n];
#pragma unroll
      for (int r = 0; r < 4; ++r) {
        int tok = 16 * wid + l4 * 4 + r;
        float vv = acc[nf][r] + bias;
        vv = 0.5f * vv * (1.f + erff(vv * 0.70710678118654752f));
        ldss(hbuf, tok, 512, n, 7, f2bf(vv));
      }
    }
  }
  __syncthreads();
  // fc2 + residual (in-place)
  {
    f32x4 acc[8];
#pragma unroll
    for (int nf = 0; nf < 8; ++nf) acc[nf] = fzero;
    for (int kk = 0; kk < 16; ++kk) {
      const int kh = kk * 32 + l4 * 8;
      bf16x8 a = ldsv(hbuf, 16 * wid + l15, 512, kh, 7);
#pragma unroll
      for (int nf = 0; nf < 8; ++nf) {
        int n = nf * 16 + l15;
        bf16x8 bb = *(const bf16x8*)(Wfc2 + n * 512 + kh);
        acc[nf] = __builtin_amdgcn_mfma_f32_16x16x32_bf16(a, bb, acc[nf], 0, 0, 0);
      }
    }
#pragma unroll
    for (int nf = 0; nf < 8; ++nf) {
      int col = nf * 16 + l15;
      float bias = fc2b[col];
#pragma unroll
      for (int r = 0; r < 4; ++r) {
        int tok = 16 * wid + l4 * 4 + r;
        size_t off = (rbase + tok) * 128 + col;
        out[off] = acc[nf][r] + bias + out[off];
      }
    }
  }
}

extern "C" void kernel_launch(void* const* d_in, const int* in_sizes, int n_in,
                              void* d_out, int out_size, void* d_ws, size_t ws_size,
                              hipStream_t stream) {
  const float* x    = (const float*)d_in[0];
  const float* dd   = (const float*)d_in[1];
  const float* rpb  = (const float*)d_in[2];
  const float* n1w  = (const float*)d_in[3];
  const float* n1b  = (const float*)d_in[4];
  const float* n2w  = (const float*)d_in[5];
  const float* n2b  = (const float*)d_in[6];
  const float* qkvw = (const float*)d_in[7];
  const float* qkvb = (const float*)d_in[8];
  const float* pw   = (const float*)d_in[9];
  const float* pb   = (const float*)d_in[10];
  const float* f1w  = (const float*)d_in[11];
  const float* f1b  = (const float*)d_in[12];
  const float* f2w  = (const float*)d_in[13];
  const float* f2b  = (const float*)d_in[14];
  float* out = (float*)d_out;
  char* ws = (char*)d_ws;
  unsigned short* Wqkv  = (unsigned short*)(ws);
  unsigned short* Wproj = (unsigned short*)(ws + 131072);
  unsigned short* Wfc1  = (unsigned short*)(ws + 163840);
  unsigned short* Wfc2  = (unsigned short*)(ws + 294912);
  float* bqkv           = (float*)(ws + 425984);
  float* biasmat        = (float*)(ws + 428032);

  prep_kernel<<<dim3(899), dim3(256), 0, stream>>>(qkvw, qkvb, pw, f1w, f2w, rpb,
                                                   Wqkv, Wproj, Wfc1, Wfc2, bqkv, biasmat);
  attn_kernel<<<dim3(1024), dim3(256), 0, stream>>>(x, dd, n1w, n1b, Wqkv, bqkv,
                                                    Wproj, pb, biasmat, out);
  mlp_kernel<<<dim3(2048), dim3(256), 0, stream>>>(n2w, n2b, Wfc1, f1b, Wfc2, f2b, out);
}

// Round 2
// 368.407 us; speedup vs baseline: 1.7525x; 1.7525x over previous
//
#include <hip/hip_runtime.h>
#include <math.h>

typedef short bf16x8 __attribute__((ext_vector_type(8)));
typedef float f32x4 __attribute__((ext_vector_type(4)));

#define QKSCALE 0.17677669529663687f  // 32^-0.5

__device__ __forceinline__ unsigned short f2bf(float f) {
  unsigned int u = __float_as_uint(f);
  u = (u + 0x7FFFu + ((u >> 16) & 1u)) >> 16;
  return (unsigned short)u;
}
__device__ __forceinline__ float bf2f(unsigned short h) {
  return __uint_as_float(((unsigned int)h) << 16);
}

// XOR-swizzled LDS helpers: row-major [rows][strideHalfs] bf16 tiles.
__device__ __forceinline__ bf16x8 ldsv(const unsigned short* base, int row, int strideHalfs, int kHalf, int swzMask) {
  int byte = row * strideHalfs * 2 + kHalf * 2;
  byte ^= (row & swzMask) << 4;
  return *(const bf16x8*)((const char*)base + byte);
}
__device__ __forceinline__ void ldss(unsigned short* base, int row, int strideHalfs, int col, int swzMask, unsigned short v) {
  int byte = row * strideHalfs * 2 + col * 2;
  byte ^= (row & swzMask) << 4;
  *(unsigned short*)((char*)base + byte) = v;
}
__device__ __forceinline__ unsigned short ldsl(const unsigned short* base, int row, int strideHalfs, int col, int swzMask) {
  int byte = row * strideHalfs * 2 + col * 2;
  byte ^= (row & swzMask) << 4;
  return *(const unsigned short*)((const char*)base + byte);
}

// ---------------- prep: bf16 weights (+SCALE folded into q rows) + bias matrix ----------------
__global__ void prep_kernel(
    const float* __restrict__ qkv1_w, const float* __restrict__ qkv1_b,
    const float* __restrict__ proj_w, const float* __restrict__ fc1_w,
    const float* __restrict__ fc2_w,  const float* __restrict__ rpb,
    unsigned short* __restrict__ Wqkv, unsigned short* __restrict__ Wproj,
    unsigned short* __restrict__ Wfc1, unsigned short* __restrict__ Wfc2,
    float* __restrict__ bqkv, float* __restrict__ biasmat)
{
  int i = blockIdx.x * 256 + threadIdx.x;
  if (i < 65536) {  // qkv1_w (512,128), comp = row>>7; scale q (0) and q2 (3)
    int row = i >> 7, comp = row >> 7;
    float sc = (comp == 0 || comp == 3) ? QKSCALE : 1.f;
    Wqkv[i] = f2bf(qkv1_w[i] * sc);
  }
  int j = i - 65536;
  if (j >= 0 && j < 16384) Wproj[j] = f2bf(proj_w[j]);
  j -= 16384;
  if (j >= 0 && j < 65536) Wfc1[j] = f2bf(fc1_w[j]);
  j -= 65536;
  if (j >= 0 && j < 65536) Wfc2[j] = f2bf(fc2_w[j]);
  j -= 65536;
  if (j >= 0 && j < 512) {
    int comp = j >> 7;
    bqkv[j] = qkv1_b[j] * ((comp == 0 || comp == 3) ? QKSCALE : 1.f);
  }
  j -= 512;
  if (j >= 0 && j < 16384) {  // biasmat[h][n][m]
    int hh = j >> 12, n = (j >> 6) & 63, m = j & 63;
    int di = (n >> 3) - (m >> 3) + 7, dj = (n & 7) - (m & 7) + 7;
    biasmat[j] = rpb[(di * 15 + dj) * 4 + hh];
  }
}

// ---------------- attention: 1 block = (window, head), both streams ----------------
// LDS 48KB -> 3 blocks/CU. 3 barriers per block.
__global__ void __launch_bounds__(256, 3) attn_kernel(
    const float* __restrict__ x_in, const float* __restrict__ d_in_,
    const float* __restrict__ n1w, const float* __restrict__ n1b,
    const unsigned short* __restrict__ Wqkv, const float* __restrict__ bqkv,
    const float* __restrict__ biasmat,
    unsigned short* __restrict__ aout)
{
  __shared__ unsigned short qkbuf[2][4][64 * 32];  // per stream: q,k,vt([32][64]),q2 ; 32KB
  __shared__ unsigned short Pbuf[2][64 * 64];      // 16KB

  const int tid = threadIdx.x, wid = tid >> 6, lane = tid & 63;
  const int l4 = lane >> 4, l15 = lane & 15;
  const int win = blockIdx.x >> 2, h = blockIdx.x & 3;
  const int b = win >> 8, hb = (win >> 4) & 15, wb = win & 15;
  const int base_row = b * 16384 + hb * 1024 + wb * 8;

  // ---- LN1 straight into A-register fragments ----
  // lane handles token wid*16+l15, channels kk*32+l4*8 .. +8 (exactly MFMA A layout)
  bf16x8 aF[2][4];
  {
    const int tok = wid * 16 + l15;
    const int grow = base_row + (tok >> 3) * 128 + (tok & 7);
    for (int s = 0; s < 2; ++s) {
      const float* src = (s ? d_in_ : x_in) + (size_t)grow * 128;
      float v[32];
      float sum = 0.f, ss = 0.f;
#pragma unroll
      for (int kk = 0; kk < 4; ++kk) {
        float4 f0 = *(const float4*)(src + kk * 32 + l4 * 8);
        float4 f1 = *(const float4*)(src + kk * 32 + l4 * 8 + 4);
        v[kk * 8 + 0] = f0.x; v[kk * 8 + 1] = f0.y; v[kk * 8 + 2] = f0.z; v[kk * 8 + 3] = f0.w;
        v[kk * 8 + 4] = f1.x; v[kk * 8 + 5] = f1.y; v[kk * 8 + 6] = f1.z; v[kk * 8 + 7] = f1.w;
        sum += f0.x + f0.y + f0.z + f0.w + f1.x + f1.y + f1.z + f1.w;
        ss += f0.x * f0.x + f0.y * f0.y + f0.z * f0.z + f0.w * f0.w
            + f1.x * f1.x + f1.y * f1.y + f1.z * f1.z + f1.w * f1.w;
      }
      sum += __shfl_xor(sum, 16); sum += __shfl_xor(sum, 32);
      ss  += __shfl_xor(ss, 16);  ss  += __shfl_xor(ss, 32);
      float mean = sum * (1.f / 128.f);
      float var = ss * (1.f / 128.f) - mean * mean;
      float rs = rsqrtf(var + 1e-5f);
#pragma unroll
      for (int kk = 0; kk < 4; ++kk)
#pragma unroll
        for (int jj = 0; jj < 8; ++jj) {
          int c = kk * 32 + l4 * 8 + jj;
          aF[s][kk][jj] = (short)f2bf((v[kk * 8 + jj] - mean) * rs * n1w[c] + n1b[c]);
        }
    }
  }

  const f32x4 fzero = {0.f, 0.f, 0.f, 0.f};
  // ---- QKV for this head: M=16/wave per stream, N=128 (4 comps x 32), K=128 ----
  {
    f32x4 acc[2][8];
#pragma unroll
    for (int s = 0; s < 2; ++s)
#pragma unroll
      for (int n = 0; n < 8; ++n) acc[s][n] = fzero;
#pragma unroll
    for (int kk = 0; kk < 4; ++kk)
#pragma unroll
      for (int nf = 0; nf < 8; ++nf) {
        const int nl = nf * 16 + l15;
        const int comp = nl >> 5, sub = nl & 31;
        bf16x8 bb = *(const bf16x8*)(Wqkv + (comp * 128 + h * 32 + sub) * 128 + kk * 32 + l4 * 8);
        acc[0][nf] = __builtin_amdgcn_mfma_f32_16x16x32_bf16(aF[0][kk], bb, acc[0][nf], 0, 0, 0);
        acc[1][nf] = __builtin_amdgcn_mfma_f32_16x16x32_bf16(aF[1][kk], bb, acc[1][nf], 0, 0, 0);
      }
#pragma unroll
    for (int s = 0; s < 2; ++s)
#pragma unroll
      for (int nf = 0; nf < 8; ++nf) {
        const int nl = nf * 16 + l15;
        const int comp = nl >> 5, sub = nl & 31;
        const float bias = bqkv[comp * 128 + h * 32 + sub];
#pragma unroll
        for (int r = 0; r < 4; ++r) {
          const int tw = wid * 16 + l4 * 4 + r;
          unsigned short hv = f2bf(acc[s][nf][r] + bias);
          if (comp == 2) ldss(qkbuf[s][2], sub, 64, tw, 7, hv);  // vt [32 hd][64 tok]
          else           ldss(qkbuf[s][comp], tw, 32, sub, 3, hv);
        }
      }
  }
  __syncthreads();

  // ---- scores: wave -> (stream s, kind). Full 64x64 per wave. ----
  const int s = wid >> 1, kind = wid & 1;
  f32x4 sc[4][4];
#pragma unroll
  for (int mf = 0; mf < 4; ++mf)
#pragma unroll
    for (int nf = 0; nf < 4; ++nf) sc[mf][nf] = fzero;
  {
    const unsigned short* Ab = kind ? qkbuf[1 - s][3] : qkbuf[s][0];
    const unsigned short* Kb = qkbuf[s][1];
    bf16x8 bfr[4];
#pragma unroll
    for (int nf = 0; nf < 4; ++nf) bfr[nf] = ldsv(Kb, nf * 16 + l15, 32, l4 * 8, 3);
#pragma unroll
    for (int mf = 0; mf < 4; ++mf) {
      bf16x8 a = ldsv(Ab, mf * 16 + l15, 32, l4 * 8, 3);
#pragma unroll
      for (int nf = 0; nf < 4; ++nf)
        sc[mf][nf] = __builtin_amdgcn_mfma_f32_16x16x32_bf16(a, bfr[nf], sc[mf][nf], 0, 0, 0);
    }
  }
  if (s == 0 && kind == 0) {  // rel-pos bias only on the r-branch
#pragma unroll
    for (int mf = 0; mf < 4; ++mf)
#pragma unroll
      for (int nf = 0; nf < 4; ++nf)
#pragma unroll
        for (int r = 0; r < 4; ++r) {
          int row = mf * 16 + l4 * 4 + r, col = nf * 16 + l15;
          sc[mf][nf][r] += biasmat[(h * 64 + row) * 64 + col];
        }
  }
  // in-register softmax per row (row spread over 16 lanes via l15)
#pragma unroll
  for (int mf = 0; mf < 4; ++mf)
#pragma unroll
    for (int r = 0; r < 4; ++r) {
      float v0 = sc[mf][0][r], v1 = sc[mf][1][r], v2 = sc[mf][2][r], v3 = sc[mf][3][r];
      float m = fmaxf(fmaxf(v0, v1), fmaxf(v2, v3));
      m = fmaxf(m, __shfl_xor(m, 1));
      m = fmaxf(m, __shfl_xor(m, 2));
      m = fmaxf(m, __shfl_xor(m, 4));
      m = fmaxf(m, __shfl_xor(m, 8));
      float e0 = __expf(v0 - m), e1 = __expf(v1 - m), e2 = __expf(v2 - m), e3 = __expf(v3 - m);
      float sm = e0 + e1 + e2 + e3;
      sm += __shfl_xor(sm, 1); sm += __shfl_xor(sm, 2);
      sm += __shfl_xor(sm, 4); sm += __shfl_xor(sm, 8);
      float inv = 1.f / sm;
      sc[mf][0][r] = e0 * inv; sc[mf][1][r] = e1 * inv;
      sc[mf][2][r] = e2 * inv; sc[mf][3][r] = e3 * inv;
    }
  // combine P = Pa + Pb through LDS
  if (kind == 1) {
#pragma unroll
    for (int mf = 0; mf < 4; ++mf)
#pragma unroll
      for (int nf = 0; nf < 4; ++nf)
#pragma unroll
        for (int r = 0; r < 4; ++r)
          ldss(Pbuf[s], mf * 16 + l4 * 4 + r, 64, nf * 16 + l15, 7, f2bf(sc[mf][nf][r]));
  }
  __syncthreads();
  if (kind == 0) {
#pragma unroll
    for (int mf = 0; mf < 4; ++mf)
#pragma unroll
      for (int nf = 0; nf < 4; ++nf)
#pragma unroll
        for (int r = 0; r < 4; ++r) {
          int row = mf * 16 + l4 * 4 + r, col = nf * 16 + l15;
          float cur = bf2f(ldsl(Pbuf[s], row, 64, col, 7));
          ldss(Pbuf[s], row, 64, col, 7, f2bf(cur + sc[mf][nf][r]));
        }
  }
  __syncthreads();
  // ---- PV: wave handles rows kind*32..+32, out 32 hd cols ----
  {
    f32x4 pv[2][2];
    pv[0][0] = fzero; pv[0][1] = fzero; pv[1][0] = fzero; pv[1][1] = fzero;
#pragma unroll
    for (int kk = 0; kk < 2; ++kk) {
      bf16x8 pa0 = ldsv(Pbuf[s], kind * 32 + l15, 64, kk * 32 + l4 * 8, 7);
      bf16x8 pa1 = ldsv(Pbuf[s], kind * 32 + 16 + l15, 64, kk * 32 + l4 * 8, 7);
#pragma unroll
      for (int nf = 0; nf < 2; ++nf) {
        bf16x8 bb = ldsv(qkbuf[s][2], nf * 16 + l15, 64, kk * 32 + l4 * 8, 7);
        pv[0][nf] = __builtin_amdgcn_mfma_f32_16x16x32_bf16(pa0, bb, pv[0][nf], 0, 0, 0);
        pv[1][nf] = __builtin_amdgcn_mfma_f32_16x16x32_bf16(pa1, bb, pv[1][nf], 0, 0, 0);
      }
    }
#pragma unroll
    for (int mf = 0; mf < 2; ++mf)
#pragma unroll
      for (int nf = 0; nf < 2; ++nf)
#pragma unroll
        for (int r = 0; r < 4; ++r) {
          int tw = kind * 32 + mf * 16 + l4 * 4 + r;
          aout[((size_t)s * 65536 + (size_t)win * 64 + tw) * 128 + h * 32 + nf * 16 + l15] =
              f2bf(pv[mf][nf][r]);
        }
  }
}

// ---------------- proj GEMM + residual + window-reverse (no LDS) ----------------
__global__ void __launch_bounds__(256, 4) proj_kernel(
    const unsigned short* __restrict__ aout, const unsigned short* __restrict__ Wproj,
    const float* __restrict__ projb,
    const float* __restrict__ x_in, const float* __restrict__ d_in_,
    float* __restrict__ out)
{
  const int tid = threadIdx.x, wid = tid >> 6, lane = tid & 63;
  const int l4 = lane >> 4, l15 = lane & 15;
  const int s = blockIdx.x >> 9, blk = blockIdx.x & 511;
  const int row0 = blk * 128 + wid * 32;
  const unsigned short* A = aout + (size_t)s * 65536 * 128;
  const f32x4 fzero = {0.f, 0.f, 0.f, 0.f};

  bf16x8 aF[2][4];
#pragma unroll
  for (int mf = 0; mf < 2; ++mf)
#pragma unroll
    for (int kk = 0; kk < 4; ++kk)
      aF[mf][kk] = *(const bf16x8*)(A + (size_t)(row0 + mf * 16 + l15) * 128 + kk * 32 + l4 * 8);

  f32x4 acc[2][8];
#pragma unroll
  for (int mf = 0; mf < 2; ++mf)
#pragma unroll
    for (int nf = 0; nf < 8; ++nf) acc[mf][nf] = fzero;
#pragma unroll
  for (int kk = 0; kk < 4; ++kk)
#pragma unroll
    for (int nf = 0; nf < 8; ++nf) {
      bf16x8 bb = *(const bf16x8*)(Wproj + (nf * 16 + l15) * 128 + kk * 32 + l4 * 8);
      acc[0][nf] = __builtin_amdgcn_mfma_f32_16x16x32_bf16(aF[0][kk], bb, acc[0][nf], 0, 0, 0);
      acc[1][nf] = __builtin_amdgcn_mfma_f32_16x16x32_bf16(aF[1][kk], bb, acc[1][nf], 0, 0, 0);
    }

  const float* resid = s ? d_in_ : x_in;
  float* dst = out + (size_t)s * 8388608;
#pragma unroll
  for (int mf = 0; mf < 2; ++mf)
#pragma unroll
    for (int nf = 0; nf < 8; ++nf) {
      int col = nf * 16 + l15;
      float pb = projb[col];
#pragma unroll
      for (int r = 0; r < 4; ++r) {
        int t = row0 + mf * 16 + l4 * 4 + r;
        int w2 = t >> 6, tk = t & 63;
        int b2 = w2 >> 8, hb = (w2 >> 4) & 15, wb = w2 & 15;
        int grow = b2 * 16384 + hb * 1024 + (tk >> 3) * 128 + wb * 8 + (tk & 7);
        size_t off = (size_t)grow * 128 + col;
        dst[off] = acc[mf][nf][r] + pb + resid[off];
      }
    }
}

// ---------------- MLP: 1 block = 32 tokens (LDS 40KB -> 4 blocks/CU) ----------------
__global__ void __launch_bounds__(256, 4) mlp_kernel(
    const float* __restrict__ n2w, const float* __restrict__ n2b,
    const unsigned short* __restrict__ Wfc1, const float* __restrict__ fc1b,
    const unsigned short* __restrict__ Wfc2, const float* __restrict__ fc2b,
    float* __restrict__ out)
{
  __shared__ unsigned short xn[32 * 128];    // 8KB  (mask 7)
  __shared__ unsigned short hbuf[32 * 512];  // 32KB (mask 7)
  const int tid = threadIdx.x, wid = tid >> 6, lane = tid & 63;
  const int l4 = lane >> 4, l15 = lane & 15;
  const size_t rbase = (size_t)blockIdx.x * 32;
  const f32x4 fzero = {0.f, 0.f, 0.f, 0.f};

  // LN2: 8 lanes per token, 16 ch each
  {
    const int t = tid >> 3, q8 = tid & 7;
    const float* src = out + (rbase + t) * 128 + q8 * 16;
    float v[16];
    float sum = 0.f, ss = 0.f;
#pragma unroll
    for (int i = 0; i < 4; ++i) {
      float4 f = ((const float4*)src)[i];
      v[i * 4 + 0] = f.x; v[i * 4 + 1] = f.y; v[i * 4 + 2] = f.z; v[i * 4 + 3] = f.w;
      sum += f.x + f.y + f.z + f.w;
      ss += f.x * f.x + f.y * f.y + f.z * f.z + f.w * f.w;
    }
    sum += __shfl_xor(sum, 1); sum += __shfl_xor(sum, 2); sum += __shfl_xor(sum, 4);
    ss  += __shfl_xor(ss, 1);  ss  += __shfl_xor(ss, 2);  ss  += __shfl_xor(ss, 4);
    float mean = sum * (1.f / 128.f), var = ss * (1.f / 128.f) - mean * mean;
    float rs = rsqrtf(var + 1e-5f);
#pragma unroll
    for (int i = 0; i < 16; ++i) {
      int c = q8 * 16 + i;
      ldss(xn, t, 128, c, 7, f2bf((v[i] - mean) * rs * n2w[c] + n2b[c]));
    }
  }
  __syncthreads();
  // fc1 + exact gelu: wave w owns N chunk w*128..+128
  {
    bf16x8 aF[2][4];
#pragma unroll
    for (int mf = 0; mf < 2; ++mf)
#pragma unroll
      for (int kk = 0; kk < 4; ++kk)
        aF[mf][kk] = ldsv(xn, mf * 16 + l15, 128, kk * 32 + l4 * 8, 7);
    f32x4 acc[2][8];
#pragma unroll
    for (int mf = 0; mf < 2; ++mf)
#pragma unroll
      for (int nf = 0; nf < 8; ++nf) acc[mf][nf] = fzero;
#pragma unroll
    for (int kk = 0; kk < 4; ++kk)
#pragma unroll
      for (int nf = 0; nf < 8; ++nf) {
        int n = wid * 128 + nf * 16 + l15;
        bf16x8 bb = *(const bf16x8*)(Wfc1 + (size_t)n * 128 + kk * 32 + l4 * 8);
        acc[0][nf] = __builtin_amdgcn_mfma_f32_16x16x32_bf16(aF[0][kk], bb, acc[0][nf], 0, 0, 0);
        acc[1][nf] = __builtin_amdgcn_mfma_f32_16x16x32_bf16(aF[1][kk], bb, acc[1][nf], 0, 0, 0);
      }
#pragma unroll
    for (int mf = 0; mf < 2; ++mf)
#pragma unroll
      for (int nf = 0; nf < 8; ++nf) {
        int n = wid * 128 + nf * 16 + l15;
        float bias = fc1b[n];
#pragma unroll
        for (int r = 0; r < 4; ++r) {
          int row = mf * 16 + l4 * 4 + r;
          float vv = acc[mf][nf][r] + bias;
          vv = 0.5f * vv * (1.f + erff(vv * 0.70710678118654752f));
          ldss(hbuf, row, 512, n, 7, f2bf(vv));
        }
      }
  }
  __syncthreads();
  // fc2 + residual: wave w owns N chunk w*32..+32, K=512
  {
    f32x4 a2[2][2];
    a2[0][0] = fzero; a2[0][1] = fzero; a2[1][0] = fzero; a2[1][1] = fzero;
    for (int kk = 0; kk < 16; ++kk) {
      bf16x8 h0 = ldsv(hbuf, l15, 512, kk * 32 + l4 * 8, 7);
      bf16x8 h1 = ldsv(hbuf, 16 + l15, 512, kk * 32 + l4 * 8, 7);
#pragma unroll
      for (int nf = 0; nf < 2; ++nf) {
        int n = wid * 32 + nf * 16 + l15;
        bf16x8 bb = *(const bf16x8*)(Wfc2 + (size_t)n * 512 + kk * 32 + l4 * 8);
        a2[0][nf] = __builtin_amdgcn_mfma_f32_16x16x32_bf16(h0, bb, a2[0][nf], 0, 0, 0);
        a2[1][nf] = __builtin_amdgcn_mfma_f32_16x16x32_bf16(h1, bb, a2[1][nf], 0, 0, 0);
      }
    }
#pragma unroll
    for (int mf = 0; mf < 2; ++mf)
#pragma unroll
      for (int nf = 0; nf < 2; ++nf) {
        int col = wid * 32 + nf * 16 + l15;
        float bias = fc2b[col];
#pragma unroll
        for (int r = 0; r < 4; ++r) {
          int row = mf * 16 + l4 * 4 + r;
          size_t off = (rbase + row) * 128 + col;
          out[off] = a2[mf][nf][r] + bias + out[off];
        }
      }
  }
}

extern "C" void kernel_launch(void* const* d_in, const int* in_sizes, int n_in,
                              void* d_out, int out_size, void* d_ws, size_t ws_size,
                              hipStream_t stream) {
  const float* x    = (const float*)d_in[0];
  const float* dd   = (const float*)d_in[1];
  const float* rpb  = (const float*)d_in[2];
  const float* n1w  = (const float*)d_in[3];
  const float* n1b  = (const float*)d_in[4];
  const float* n2w  = (const float*)d_in[5];
  const float* n2b  = (const float*)d_in[6];
  const float* qkvw = (const float*)d_in[7];
  const float* qkvb = (const float*)d_in[8];
  const float* pw   = (const float*)d_in[9];
  const float* pb   = (const float*)d_in[10];
  const float* f1w  = (const float*)d_in[11];
  const float* f1b  = (const float*)d_in[12];
  const float* f2w  = (const float*)d_in[13];
  const float* f2b  = (const float*)d_in[14];
  float* out = (float*)d_out;
  char* ws = (char*)d_ws;
  unsigned short* Wqkv  = (unsigned short*)(ws);
  unsigned short* Wproj = (unsigned short*)(ws + 131072);
  unsigned short* Wfc1  = (unsigned short*)(ws + 163840);
  unsigned short* Wfc2  = (unsigned short*)(ws + 294912);
  float* bqkv           = (float*)(ws + 425984);
  float* biasmat        = (float*)(ws + 428032);
  unsigned short* aout  = (unsigned short*)(ws + 524288);  // 2*65536*128 bf16 = 33.5MB

  prep_kernel<<<dim3(899), dim3(256), 0, stream>>>(qkvw, qkvb, pw, f1w, f2w, rpb,
                                                   Wqkv, Wproj, Wfc1, Wfc2, bqkv, biasmat);
  attn_kernel<<<dim3(4096), dim3(256), 0, stream>>>(x, dd, n1w, n1b, Wqkv, bqkv, biasmat, aout);
  proj_kernel<<<dim3(1024), dim3(256), 0, stream>>>(aout, Wproj, pb, x, dd, out);
  mlp_kernel<<<dim3(4096), dim3(256), 0, stream>>>(n2w, n2b, Wfc1, f1b, Wfc2, f2b, out);
}

// Round 4
// 341.885 us; speedup vs baseline: 1.8885x; 1.0776x over previous
//
#include <hip/hip_runtime.h>
#include <math.h>

typedef short bf16x8 __attribute__((ext_vector_type(8)));
typedef float f32x4 __attribute__((ext_vector_type(4)));

#define QKSCALE 0.17677669529663687f  // 32^-0.5

__device__ __forceinline__ unsigned short f2bf(float f) {
  unsigned int u = __float_as_uint(f);
  u = (u + 0x7FFFu + ((u >> 16) & 1u)) >> 16;
  return (unsigned short)u;
}
__device__ __forceinline__ float bf2f(unsigned short h) {
  return __uint_as_float(((unsigned int)h) << 16);
}

// XOR-swizzled LDS helpers: row-major [rows][strideHalfs] bf16 tiles.
__device__ __forceinline__ bf16x8 ldsv(const unsigned short* base, int row, int strideHalfs, int kHalf, int swzMask) {
  int byte = row * strideHalfs * 2 + kHalf * 2;
  byte ^= (row & swzMask) << 4;
  return *(const bf16x8*)((const char*)base + byte);
}
__device__ __forceinline__ void ldss(unsigned short* base, int row, int strideHalfs, int col, int swzMask, unsigned short v) {
  int byte = row * strideHalfs * 2 + col * 2;
  byte ^= (row & swzMask) << 4;
  *(unsigned short*)((char*)base + byte) = v;
}
__device__ __forceinline__ unsigned short ldsl(const unsigned short* base, int row, int strideHalfs, int col, int swzMask) {
  int byte = row * strideHalfs * 2 + col * 2;
  byte ^= (row & swzMask) << 4;
  return *(const unsigned short*)((const char*)base + byte);
}

// ---------------- prep: bf16 weights (+SCALE folded into q rows) + bias matrix ----------------
__global__ void prep_kernel(
    const float* __restrict__ qkv1_w, const float* __restrict__ qkv1_b,
    const float* __restrict__ proj_w, const float* __restrict__ fc1_w,
    const float* __restrict__ fc2_w,  const float* __restrict__ rpb,
    unsigned short* __restrict__ Wqkv, unsigned short* __restrict__ Wproj,
    unsigned short* __restrict__ Wfc1, unsigned short* __restrict__ Wfc2,
    float* __restrict__ bqkv, float* __restrict__ biasmat)
{
  int i = blockIdx.x * 256 + threadIdx.x;
  if (i < 65536) {  // qkv1_w (512,128), comp = row>>7; scale q (0) and q2 (3)
    int row = i >> 7, comp = row >> 7;
    float sc = (comp == 0 || comp == 3) ? QKSCALE : 1.f;
    Wqkv[i] = f2bf(qkv1_w[i] * sc);
  }
  int j = i - 65536;
  if (j >= 0 && j < 16384) Wproj[j] = f2bf(proj_w[j]);
  j -= 16384;
  if (j >= 0 && j < 65536) Wfc1[j] = f2bf(fc1_w[j]);
  j -= 65536;
  if (j >= 0 && j < 65536) Wfc2[j] = f2bf(fc2_w[j]);
  j -= 65536;
  if (j >= 0 && j < 512) {
    int comp = j >> 7;
    bqkv[j] = qkv1_b[j] * ((comp == 0 || comp == 3) ? QKSCALE : 1.f);
  }
  j -= 512;
  if (j >= 0 && j < 16384) {  // biasmat[h][n][m]
    int hh = j >> 12, n = (j >> 6) & 63, m = j & 63;
    int di = (n >> 3) - (m >> 3) + 7, dj = (n & 7) - (m & 7) + 7;
    biasmat[j] = rpb[(di * 15 + dj) * 4 + hh];
  }
}

// ---------------- LN1 both streams -> window-ordered bf16 tokens (in d_out scratch) ----------------
// grid: 2048 blocks = 2 streams x 1024 blocks x 64 rows
__global__ void __launch_bounds__(256) ln1_kernel(
    const float* __restrict__ x_in, const float* __restrict__ d_in_,
    const float* __restrict__ n1w, const float* __restrict__ n1b,
    unsigned short* __restrict__ xg)  // [2][65536][128]
{
  const int s = blockIdx.x >> 10;
  const int row0 = (blockIdx.x & 1023) * 64;
  const int t = threadIdx.x >> 2, q4 = threadIdx.x & 3;
  const int grow = row0 + t;                 // global row within stream (0..65535)
  const int b2 = grow >> 14, rem = grow & 16383;
  const int gy = rem >> 7, gx = rem & 127;
  const int win = b2 * 256 + (gy >> 3) * 16 + (gx >> 3);
  const int tok = (gy & 7) * 8 + (gx & 7);
  const float* src = (s ? d_in_ : x_in) + (size_t)grow * 128 + q4 * 32;
  float v[32];
  float sum = 0.f, ss = 0.f;
#pragma unroll
  for (int i = 0; i < 8; ++i) {
    float4 f = ((const float4*)src)[i];
    v[i * 4 + 0] = f.x; v[i * 4 + 1] = f.y; v[i * 4 + 2] = f.z; v[i * 4 + 3] = f.w;
    sum += f.x + f.y + f.z + f.w;
    ss += f.x * f.x + f.y * f.y + f.z * f.z + f.w * f.w;
  }
  sum += __shfl_xor(sum, 1); sum += __shfl_xor(sum, 2);
  ss  += __shfl_xor(ss, 1);  ss  += __shfl_xor(ss, 2);
  float mean = sum * (1.f / 128.f);
  float var = ss * (1.f / 128.f) - mean * mean;
  float rs = rsqrtf(var + 1e-5f);
  unsigned short* dst = xg + ((size_t)s * 65536 + (size_t)win * 64 + tok) * 128 + q4 * 32;
#pragma unroll
  for (int i = 0; i < 4; ++i) {
    bf16x8 o;
#pragma unroll
    for (int jj = 0; jj < 8; ++jj) {
      int c = q4 * 32 + i * 8 + jj;
      o[jj] = (short)f2bf((v[i * 8 + jj] - mean) * rs * n1w[c] + n1b[c]);
    }
    *(bf16x8*)(dst + i * 8) = o;
  }
}

// ---------------- attention: 1 block = (window, head), both streams ----------------
// LDS 32KB (P aliased over q/q2). 4 barriers.
__global__ void __launch_bounds__(256, 4) attn_kernel(
    const unsigned short* __restrict__ xg,
    const unsigned short* __restrict__ Wqkv, const float* __restrict__ bqkv,
    const float* __restrict__ biasmat,
    unsigned short* __restrict__ aout)
{
  // per stream (8192 halfs): q @0 (64x32,m3), q2 @2048, k @4096, vt @6144 ([32][64],m7)
  // P aliases @0..4095 ([64][64], m7)
  __shared__ unsigned short smem[2][8192];

  const int tid = threadIdx.x, wid = tid >> 6, lane = tid & 63;
  const int l4 = lane >> 4, l15 = lane & 15;
  const int win = blockIdx.x >> 2, h = blockIdx.x & 3;
  const f32x4 fzero = {0.f, 0.f, 0.f, 0.f};

  // ---- A-fragments straight from pre-LN'd bf16 ----
  bf16x8 aF[2][4];
#pragma unroll
  for (int s = 0; s < 2; ++s) {
    const unsigned short* Ax = xg + ((size_t)s * 65536 + (size_t)win * 64 + wid * 16 + l15) * 128 + l4 * 8;
#pragma unroll
    for (int kk = 0; kk < 4; ++kk) aF[s][kk] = *(const bf16x8*)(Ax + kk * 32);
  }

  // ---- QKV for this head: M=16/wave per stream, N=128 (4 comps x 32), K=128 ----
  {
    f32x4 acc[2][8];
#pragma unroll
    for (int s = 0; s < 2; ++s)
#pragma unroll
      for (int n = 0; n < 8; ++n) acc[s][n] = fzero;
#pragma unroll
    for (int kk = 0; kk < 4; ++kk)
#pragma unroll
      for (int nf = 0; nf < 8; ++nf) {
        const int nl = nf * 16 + l15;
        const int comp = nl >> 5, sub = nl & 31;
        bf16x8 bb = *(const bf16x8*)(Wqkv + (comp * 128 + h * 32 + sub) * 128 + kk * 32 + l4 * 8);
        acc[0][nf] = __builtin_amdgcn_mfma_f32_16x16x32_bf16(aF[0][kk], bb, acc[0][nf], 0, 0, 0);
        acc[1][nf] = __builtin_amdgcn_mfma_f32_16x16x32_bf16(aF[1][kk], bb, acc[1][nf], 0, 0, 0);
      }
#pragma unroll
    for (int s = 0; s < 2; ++s)
#pragma unroll
      for (int nf = 0; nf < 8; ++nf) {
        const int nl = nf * 16 + l15;
        const int comp = nl >> 5, sub = nl & 31;
        const float bias = bqkv[comp * 128 + h * 32 + sub];
#pragma unroll
        for (int r = 0; r < 4; ++r) {
          const int tw = wid * 16 + l4 * 4 + r;
          unsigned short hv = f2bf(acc[s][nf][r] + bias);
          if (comp == 2)      ldss(smem[s] + 6144, sub, 64, tw, 7, hv);   // vt [32 hd][64 tok]
          else if (comp == 0) ldss(smem[s] + 0,    tw, 32, sub, 3, hv);   // q
          else if (comp == 1) ldss(smem[s] + 4096, tw, 32, sub, 3, hv);   // k
          else                ldss(smem[s] + 2048, tw, 32, sub, 3, hv);   // q2
        }
      }
  }
  __syncthreads();

  // ---- score phase: wave -> (stream s, kind). Read A/K into regs, then sync (alias safety). ----
  const int s = wid >> 1, kind = wid & 1;
  bf16x8 aR[4], kR[4];
  {
    const unsigned short* Ab = kind ? (smem[1 - s] + 2048) : (smem[s] + 0);
    const unsigned short* Kb = smem[s] + 4096;
#pragma unroll
    for (int mf = 0; mf < 4; ++mf) aR[mf] = ldsv(Ab, mf * 16 + l15, 32, l4 * 8, 3);
#pragma unroll
    for (int nf = 0; nf < 4; ++nf) kR[nf] = ldsv(Kb, nf * 16 + l15, 32, l4 * 8, 3);
  }
  __syncthreads();

  f32x4 sc[4][4];
#pragma unroll
  for (int mf = 0; mf < 4; ++mf)
#pragma unroll
    for (int nf = 0; nf < 4; ++nf) sc[mf][nf] = fzero;
#pragma unroll
  for (int mf = 0; mf < 4; ++mf)
#pragma unroll
    for (int nf = 0; nf < 4; ++nf)
      sc[mf][nf] = __builtin_amdgcn_mfma_f32_16x16x32_bf16(aR[mf], kR[nf], sc[mf][nf], 0, 0, 0);

  if (s == 0 && kind == 0) {  // rel-pos bias only on the r-branch
#pragma unroll
    for (int mf = 0; mf < 4; ++mf)
#pragma unroll
      for (int nf = 0; nf < 4; ++nf)
#pragma unroll
        for (int r = 0; r < 4; ++r) {
          int row = mf * 16 + l4 * 4 + r, col = nf * 16 + l15;
          sc[mf][nf][r] += biasmat[(h * 64 + row) * 64 + col];
        }
  }
  // in-register softmax per row (row spread over 16 lanes via l15)
#pragma unroll
  for (int mf = 0; mf < 4; ++mf)
#pragma unroll
    for (int r = 0; r < 4; ++r) {
      float v0 = sc[mf][0][r], v1 = sc[mf][1][r], v2 = sc[mf][2][r], v3 = sc[mf][3][r];
      float m = fmaxf(fmaxf(v0, v1), fmaxf(v2, v3));
      m = fmaxf(m, __shfl_xor(m, 1));
      m = fmaxf(m, __shfl_xor(m, 2));
      m = fmaxf(m, __shfl_xor(m, 4));
      m = fmaxf(m, __shfl_xor(m, 8));
      float e0 = __expf(v0 - m), e1 = __expf(v1 - m), e2 = __expf(v2 - m), e3 = __expf(v3 - m);
      float sm = e0 + e1 + e2 + e3;
      sm += __shfl_xor(sm, 1); sm += __shfl_xor(sm, 2);
      sm += __shfl_xor(sm, 4); sm += __shfl_xor(sm, 8);
      float inv = 1.f / sm;
      sc[mf][0][r] = e0 * inv; sc[mf][1][r] = e1 * inv;
      sc[mf][2][r] = e2 * inv; sc[mf][3][r] = e3 * inv;
    }
  unsigned short* Ps = smem[s];  // P aliases q/q2 region, [64][64] mask7
  if (kind == 1) {
#pragma unroll
    for (int mf = 0; mf < 4; ++mf)
#pragma unroll
      for (int nf = 0; nf < 4; ++nf)
#pragma unroll
        for (int r = 0; r < 4; ++r)
          ldss(Ps, mf * 16 + l4 * 4 + r, 64, nf * 16 + l15, 7, f2bf(sc[mf][nf][r]));
  }
  __syncthreads();
  if (kind == 0) {
#pragma unroll
    for (int mf = 0; mf < 4; ++mf)
#pragma unroll
      for (int nf = 0; nf < 4; ++nf)
#pragma unroll
        for (int r = 0; r < 4; ++r) {
          int row = mf * 16 + l4 * 4 + r, col = nf * 16 + l15;
          float cur = bf2f(ldsl(Ps, row, 64, col, 7));
          ldss(Ps, row, 64, col, 7, f2bf(cur + sc[mf][nf][r]));
        }
  }
  __syncthreads();
  // ---- PV: wave handles rows kind*32..+32, out 32 hd cols ----
  {
    const unsigned short* Vt = smem[s] + 6144;
    f32x4 pv[2][2];
    pv[0][0] = fzero; pv[0][1] = fzero; pv[1][0] = fzero; pv[1][1] = fzero;
#pragma unroll
    for (int kk = 0; kk < 2; ++kk) {
      bf16x8 pa0 = ldsv(Ps, kind * 32 + l15, 64, kk * 32 + l4 * 8, 7);
      bf16x8 pa1 = ldsv(Ps, kind * 32 + 16 + l15, 64, kk * 32 + l4 * 8, 7);
#pragma unroll
      for (int nf = 0; nf < 2; ++nf) {
        bf16x8 bb = ldsv(Vt, nf * 16 + l15, 64, kk * 32 + l4 * 8, 7);
        pv[0][nf] = __builtin_amdgcn_mfma_f32_16x16x32_bf16(pa0, bb, pv[0][nf], 0, 0, 0);
        pv[1][nf] = __builtin_amdgcn_mfma_f32_16x16x32_bf16(pa1, bb, pv[1][nf], 0, 0, 0);
      }
    }
#pragma unroll
    for (int mf = 0; mf < 2; ++mf)
#pragma unroll
      for (int nf = 0; nf < 2; ++nf)
#pragma unroll
        for (int r = 0; r < 4; ++r) {
          int tw = kind * 32 + mf * 16 + l4 * 4 + r;
          aout[((size_t)s * 65536 + (size_t)win * 64 + tw) * 128 + h * 32 + nf * 16 + l15] =
              f2bf(pv[mf][nf][r]);
        }
  }
}

// ---------------- proj GEMM + residual + window-reverse (no LDS) ----------------
__global__ void __launch_bounds__(256, 4) proj_kernel(
    const unsigned short* __restrict__ aout, const unsigned short* __restrict__ Wproj,
    const float* __restrict__ projb,
    const float* __restrict__ x_in, const float* __restrict__ d_in_,
    float* __restrict__ out)
{
  const int tid = threadIdx.x, wid = tid >> 6, lane = tid & 63;
  const int l4 = lane >> 4, l15 = lane & 15;
  const int s = blockIdx.x >> 9, blk = blockIdx.x & 511;
  const int row0 = blk * 128 + wid * 32;
  const unsigned short* A = aout + (size_t)s * 65536 * 128;
  const f32x4 fzero = {0.f, 0.f, 0.f, 0.f};

  bf16x8 aF[2][4];
#pragma unroll
  for (int mf = 0; mf < 2; ++mf)
#pragma unroll
    for (int kk = 0; kk < 4; ++kk)
      aF[mf][kk] = *(const bf16x8*)(A + (size_t)(row0 + mf * 16 + l15) * 128 + kk * 32 + l4 * 8);

  f32x4 acc[2][8];
#pragma unroll
  for (int mf = 0; mf < 2; ++mf)
#pragma unroll
    for (int nf = 0; nf < 8; ++nf) acc[mf][nf] = fzero;
#pragma unroll
  for (int kk = 0; kk < 4; ++kk)
#pragma unroll
    for (int nf = 0; nf < 8; ++nf) {
      bf16x8 bb = *(const bf16x8*)(Wproj + (nf * 16 + l15) * 128 + kk * 32 + l4 * 8);
      acc[0][nf] = __builtin_amdgcn_mfma_f32_16x16x32_bf16(aF[0][kk], bb, acc[0][nf], 0, 0, 0);
      acc[1][nf] = __builtin_amdgcn_mfma_f32_16x16x32_bf16(aF[1][kk], bb, acc[1][nf], 0, 0, 0);
    }

  const float* resid = s ? d_in_ : x_in;
  float* dst = out + (size_t)s * 8388608;
#pragma unroll
  for (int mf = 0; mf < 2; ++mf)
#pragma unroll
    for (int nf = 0; nf < 8; ++nf) {
      int col = nf * 16 + l15;
      float pb = projb[col];
#pragma unroll
      for (int r = 0; r < 4; ++r) {
        int t = row0 + mf * 16 + l4 * 4 + r;
        int w2 = t >> 6, tk = t & 63;
        int b2 = w2 >> 8, hb = (w2 >> 4) & 15, wb = w2 & 15;
        int grow = b2 * 16384 + hb * 1024 + (tk >> 3) * 128 + wb * 8 + (tk & 7);
        size_t off = (size_t)grow * 128 + col;
        dst[off] = acc[mf][nf][r] + pb + resid[off];
      }
    }
}

// ---------------- MLP: 1 block = 32 tokens (LDS 40KB -> 4 blocks/CU) ----------------
__global__ void __launch_bounds__(256, 4) mlp_kernel(
    const float* __restrict__ n2w, const float* __restrict__ n2b,
    const unsigned short* __restrict__ Wfc1, const float* __restrict__ fc1b,
    const unsigned short* __restrict__ Wfc2, const float* __restrict__ fc2b,
    float* __restrict__ out)
{
  __shared__ unsigned short xn[32 * 128];    // 8KB  (mask 7)
  __shared__ unsigned short hbuf[32 * 512];  // 32KB (mask 7)
  const int tid = threadIdx.x, wid = tid >> 6, lane = tid & 63;
  const int l4 = lane >> 4, l15 = lane & 15;
  const size_t rbase = (size_t)blockIdx.x * 32;
  const f32x4 fzero = {0.f, 0.f, 0.f, 0.f};

  // LN2: 8 lanes per token, 16 ch each
  {
    const int t = tid >> 3, q8 = tid & 7;
    const float* src = out + (rbase + t) * 128 + q8 * 16;
    float v[16];
    float sum = 0.f, ss = 0.f;
#pragma unroll
    for (int i = 0; i < 4; ++i) {
      float4 f = ((const float4*)src)[i];
      v[i * 4 + 0] = f.x; v[i * 4 + 1] = f.y; v[i * 4 + 2] = f.z; v[i * 4 + 3] = f.w;
      sum += f.x + f.y + f.z + f.w;
      ss += f.x * f.x + f.y * f.y + f.z * f.z + f.w * f.w;
    }
    sum += __shfl_xor(sum, 1); sum += __shfl_xor(sum, 2); sum += __shfl_xor(sum, 4);
    ss  += __shfl_xor(ss, 1);  ss  += __shfl_xor(ss, 2);  ss  += __shfl_xor(ss, 4);
    float mean = sum * (1.f / 128.f), var = ss * (1.f / 128.f) - mean * mean;
    float rs = rsqrtf(var + 1e-5f);
#pragma unroll
    for (int i = 0; i < 16; ++i) {
      int c = q8 * 16 + i;
      ldss(xn, t, 128, c, 7, f2bf((v[i] - mean) * rs * n2w[c] + n2b[c]));
    }
  }
  __syncthreads();
  // fc1 + gelu (tanh form): wave w owns N chunk w*128..+128
  {
    bf16x8 aF[2][4];
#pragma unroll
    for (int mf = 0; mf < 2; ++mf)
#pragma unroll
      for (int kk = 0; kk < 4; ++kk)
        aF[mf][kk] = ldsv(xn, mf * 16 + l15, 128, kk * 32 + l4 * 8, 7);
    f32x4 acc[2][8];
#pragma unroll
    for (int mf = 0; mf < 2; ++mf)
#pragma unroll
      for (int nf = 0; nf < 8; ++nf) acc[mf][nf] = fzero;
#pragma unroll
    for (int kk = 0; kk < 4; ++kk)
#pragma unroll
      for (int nf = 0; nf < 8; ++nf) {
        int n = wid * 128 + nf * 16 + l15;
        bf16x8 bb = *(const bf16x8*)(Wfc1 + (size_t)n * 128 + kk * 32 + l4 * 8);
        acc[0][nf] = __builtin_amdgcn_mfma_f32_16x16x32_bf16(aF[0][kk], bb, acc[0][nf], 0, 0, 0);
        acc[1][nf] = __builtin_amdgcn_mfma_f32_16x16x32_bf16(aF[1][kk], bb, acc[1][nf], 0, 0, 0);
      }
#pragma unroll
    for (int mf = 0; mf < 2; ++mf)
#pragma unroll
      for (int nf = 0; nf < 8; ++nf) {
        int n = wid * 128 + nf * 16 + l15;
        float bias = fc1b[n];
#pragma unroll
        for (int r = 0; r < 4; ++r) {
          int row = mf * 16 + l4 * 4 + r;
          float vv = acc[mf][nf][r] + bias;
          // gelu via tanh form (|u|-safe): max |err| vs exact erf ~3e-3
          float u = vv * (0.7978845608028654f + 0.035677408136300125f * vv * vv);
          float au = fabsf(u);
          float e = __expf(-2.f * au);
          float th = (1.f - e) / (1.f + e);
          th = copysignf(th, u);
          vv = 0.5f * vv * (1.f + th);
          ldss(hbuf, row, 512, n, 7, f2bf(vv));
        }
      }
  }
  __syncthreads();
  // fc2 + residual: wave w owns N chunk w*32..+32, K=512
  {
    f32x4 a2[2][2];
    a2[0][0] = fzero; a2[0][1] = fzero; a2[1][0] = fzero; a2[1][1] = fzero;
    for (int kk = 0; kk < 16; ++kk) {
      bf16x8 h0 = ldsv(hbuf, l15, 512, kk * 32 + l4 * 8, 7);
      bf16x8 h1 = ldsv(hbuf, 16 + l15, 512, kk * 32 + l4 * 8, 7);
#pragma unroll
      for (int nf = 0; nf < 2; ++nf) {
        int n = wid * 32 + nf * 16 + l15;
        bf16x8 bb = *(const bf16x8*)(Wfc2 + (size_t)n * 512 + kk * 32 + l4 * 8);
        a2[0][nf] = __builtin_amdgcn_mfma_f32_16x16x32_bf16(h0, bb, a2[0][nf], 0, 0, 0);
        a2[1][nf] = __builtin_amdgcn_mfma_f32_16x16x32_bf16(h1, bb, a2[1][nf], 0, 0, 0);
      }
    }
#pragma unroll
    for (int mf = 0; mf < 2; ++mf)
#pragma unroll
      for (int nf = 0; nf < 2; ++nf) {
        int col = wid * 32 + nf * 16 + l15;
        float bias = fc2b[col];
#pragma unroll
        for (int r = 0; r < 4; ++r) {
          int row = mf * 16 + l4 * 4 + r;
          size_t off = (rbase + row) * 128 + col;
          out[off] = a2[mf][nf][r] + bias + out[off];
        }
      }
  }
}

extern "C" void kernel_launch(void* const* d_in, const int* in_sizes, int n_in,
                              void* d_out, int out_size, void* d_ws, size_t ws_size,
                              hipStream_t stream) {
  const float* x    = (const float*)d_in[0];
  const float* dd   = (const float*)d_in[1];
  const float* rpb  = (const float*)d_in[2];
  const float* n1w  = (const float*)d_in[3];
  const float* n1b  = (const float*)d_in[4];
  const float* n2w  = (const float*)d_in[5];
  const float* n2b  = (const float*)d_in[6];
  const float* qkvw = (const float*)d_in[7];
  const float* qkvb = (const float*)d_in[8];
  const float* pw   = (const float*)d_in[9];
  const float* pb   = (const float*)d_in[10];
  const float* f1w  = (const float*)d_in[11];
  const float* f1b  = (const float*)d_in[12];
  const float* f2w  = (const float*)d_in[13];
  const float* f2b  = (const float*)d_in[14];
  float* out = (float*)d_out;
  char* ws = (char*)d_ws;
  unsigned short* Wqkv  = (unsigned short*)(ws);
  unsigned short* Wproj = (unsigned short*)(ws + 131072);
  unsigned short* Wfc1  = (unsigned short*)(ws + 163840);
  unsigned short* Wfc2  = (unsigned short*)(ws + 294912);
  float* bqkv           = (float*)(ws + 425984);
  float* biasmat        = (float*)(ws + 428032);
  unsigned short* aout  = (unsigned short*)(ws + 524288);  // 2*65536*128 bf16 = 33.5MB
  // LN1 output staged in d_out (read by attn before proj overwrites it)
  unsigned short* xg    = (unsigned short*)d_out;

  prep_kernel<<<dim3(899), dim3(256), 0, stream>>>(qkvw, qkvb, pw, f1w, f2w, rpb,
                                                   Wqkv, Wproj, Wfc1, Wfc2, bqkv, biasmat);
  ln1_kernel<<<dim3(2048), dim3(256), 0, stream>>>(x, dd, n1w, n1b, xg);
  attn_kernel<<<dim3(4096), dim3(256), 0, stream>>>(xg, Wqkv, bqkv, biasmat, aout);
  proj_kernel<<<dim3(1024), dim3(256), 0, stream>>>(aout, Wproj, pb, x, dd, out);
  mlp_kernel<<<dim3(4096), dim3(256), 0, stream>>>(n2w, n2b, Wfc1, f1b, Wfc2, f2b, out);
}

// Round 5
// 331.515 us; speedup vs baseline: 1.9475x; 1.0313x over previous
//
#include <hip/hip_runtime.h>
#include <hip/hip_bf16.h>
#include <math.h>

typedef short bf16x8 __attribute__((ext_vector_type(8)));
typedef float f32x4 __attribute__((ext_vector_type(4)));

#define QKSCALE 0.17677669529663687f  // 32^-0.5

__device__ __forceinline__ unsigned short f2bf(float f) {
  __hip_bfloat16 h = __float2bfloat16(f);
  return *reinterpret_cast<unsigned short*>(&h);
}
__device__ __forceinline__ unsigned int pk2(float lo, float hi) {
  __hip_bfloat162 h = __float22bfloat162_rn(make_float2(lo, hi));
  return *reinterpret_cast<unsigned int*>(&h);
}
__device__ __forceinline__ bf16x8 pack8(const float* g) {
  union { unsigned int u[4]; bf16x8 v; } t;
  t.u[0] = pk2(g[0], g[1]); t.u[1] = pk2(g[2], g[3]);
  t.u[2] = pk2(g[4], g[5]); t.u[3] = pk2(g[6], g[7]);
  return t.v;
}

// XOR-swizzled LDS helpers (bf16 tiles, swizzle in 16B units on row bits)
__device__ __forceinline__ bf16x8 ldsv(const unsigned short* base, int row, int strideHalfs, int kHalf, int swzMask) {
  int byte = row * strideHalfs * 2 + kHalf * 2;
  byte ^= (row & swzMask) << 4;
  return *(const bf16x8*)((const char*)base + byte);
}
__device__ __forceinline__ void ldss(unsigned short* base, int row, int strideHalfs, int col, int swzMask, unsigned short v) {
  int byte = row * strideHalfs * 2 + col * 2;
  byte ^= (row & swzMask) << 4;
  *(unsigned short*)((char*)base + byte) = v;
}
__device__ __forceinline__ void ldst32(unsigned short* base, int row, int strideHalfs, int colHalf, int swzMask, unsigned int v) {
  int byte = row * strideHalfs * 2 + colHalf * 2;
  byte ^= (row & swzMask) << 4;
  *(unsigned int*)((char*)base + byte) = v;
}
__device__ __forceinline__ void ldst64(unsigned short* base, int row, int strideHalfs, int colHalf, int swzMask, unsigned int lo, unsigned int hi) {
  int byte = row * strideHalfs * 2 + colHalf * 2;
  byte ^= (row & swzMask) << 4;
  uint2 val; val.x = lo; val.y = hi;
  *(uint2*)((char*)base + byte) = val;
}
__device__ __forceinline__ void ldst128(unsigned short* base, int row, int strideHalfs, int colHalf, int swzMask, bf16x8 v) {
  int byte = row * strideHalfs * 2 + colHalf * 2;
  byte ^= (row & swzMask) << 4;
  *(bf16x8*)((char*)base + byte) = v;
}

// ---------------- prep: bf16 weights (+SCALE fold, +k-permutations) + bias matrix ----------------
// Permutations (contraction-index reorder, applied to BOTH operands of each GEMM):
//  pi1 (32-chunk):  c' = 2a + b   <- c = 16b + a  (b in [0,2), a in [0,16))   [q/k/q2 cols, proj k]
//  pi  (128-chunk): c' = 8a + b   <- c = 16b + a  (b in [0,8), a in [0,16))   [xn2/fc1 k, hbuf/fc2 k]
__global__ void prep_kernel(
    const float* __restrict__ qkv1_w, const float* __restrict__ qkv1_b,
    const float* __restrict__ proj_w, const float* __restrict__ fc1_w,
    const float* __restrict__ fc2_w,  const float* __restrict__ rpb,
    unsigned short* __restrict__ Wqkv, unsigned short* __restrict__ Wprojs,
    unsigned short* __restrict__ Wfc1s, unsigned short* __restrict__ Wfc2s,
    float* __restrict__ bqkv, float* __restrict__ biasmat)
{
  int i = blockIdx.x * 256 + threadIdx.x;
  if (i < 65536) {  // qkv1_w (512,128): scale q(comp0) and q2(comp3); k unpermuted
    int row = i >> 7, comp = row >> 7;
    float sc = (comp == 0 || comp == 3) ? QKSCALE : 1.f;
    Wqkv[i] = f2bf(qkv1_w[i] * sc);
  }
  int j = i - 65536;
  if (j >= 0 && j < 16384) {  // Wprojs[n][c'], c' = pi1 within 32-chunks
    int n = j >> 7, m = j & 127;
    int H = m >> 5, q = m & 31, a = q >> 1, b = q & 1;
    Wprojs[j] = f2bf(proj_w[n * 128 + H * 32 + 16 * b + a]);
  }
  j -= 16384;
  if (j >= 0 && j < 65536) {  // Wfc1s[n][c'], c' = pi on K=128
    int n = j >> 7, m = j & 127;
    Wfc1s[j] = f2bf(fc1_w[n * 128 + 16 * (m & 7) + (m >> 3)]);
  }
  j -= 65536;
  if (j >= 0 && j < 65536) {  // Wfc2s[c][m], m = pi within each 128-chunk of K=512
    int c = j >> 9, m = j & 511;
    int w = m >> 7, mm = m & 127;
    Wfc2s[j] = f2bf(fc2_w[c * 512 + w * 128 + 16 * (mm & 7) + (mm >> 3)]);
  }
  j -= 65536;
  if (j >= 0 && j < 512) {
    int comp = j >> 7;
    bqkv[j] = qkv1_b[j] * ((comp == 0 || comp == 3) ? QKSCALE : 1.f);
  }
  j -= 512;
  if (j >= 0 && j < 16384) {  // biasmat[h][n][m]
    int hh = j >> 12, n = (j >> 6) & 63, m = j & 63;
    int di = (n >> 3) - (m >> 3) + 7, dj = (n & 7) - (m & 7) + 7;
    biasmat[j] = rpb[(di * 15 + dj) * 4 + hh];
  }
}

// ---------------- LN1 both streams -> window-ordered bf16 tokens (in d_out scratch) ----------------
__global__ void __launch_bounds__(256) ln1_kernel(
    const float* __restrict__ x_in, const float* __restrict__ d_in_,
    const float* __restrict__ n1w, const float* __restrict__ n1b,
    unsigned short* __restrict__ xg)  // [2][65536][128]
{
  const int s = blockIdx.x >> 10;
  const int row0 = (blockIdx.x & 1023) * 64;
  const int t = threadIdx.x >> 2, q4 = threadIdx.x & 3;
  const int grow = row0 + t;
  const int b2 = grow >> 14, rem = grow & 16383;
  const int gy = rem >> 7, gx = rem & 127;
  const int win = b2 * 256 + (gy >> 3) * 16 + (gx >> 3);
  const int tok = (gy & 7) * 8 + (gx & 7);
  const float* src = (s ? d_in_ : x_in) + (size_t)grow * 128 + q4 * 32;
  float v[32];
  float sum = 0.f, ss = 0.f;
#pragma unroll
  for (int i = 0; i < 8; ++i) {
    float4 f = ((const float4*)src)[i];
    v[i * 4 + 0] = f.x; v[i * 4 + 1] = f.y; v[i * 4 + 2] = f.z; v[i * 4 + 3] = f.w;
    sum += f.x + f.y + f.z + f.w;
    ss += f.x * f.x + f.y * f.y + f.z * f.z + f.w * f.w;
  }
  sum += __shfl_xor(sum, 1); sum += __shfl_xor(sum, 2);
  ss  += __shfl_xor(ss, 1);  ss  += __shfl_xor(ss, 2);
  float mean = sum * (1.f / 128.f);
  float var = ss * (1.f / 128.f) - mean * mean;
  float rs = rsqrtf(var + 1e-5f);
  unsigned short* dst = xg + ((size_t)s * 65536 + (size_t)win * 64 + tok) * 128 + q4 * 32;
#pragma unroll
  for (int i = 0; i < 4; ++i) {
    float g[8];
#pragma unroll
    for (int jj = 0; jj < 8; ++jj) {
      int c = q4 * 32 + i * 8 + jj;
      g[jj] = (v[i * 8 + jj] - mean) * rs * n1w[c] + n1b[c];
    }
    *(bf16x8*)(dst + i * 8) = pack8(g);
  }
}

// ---------------- attention: 1 block = (window, head), both streams ----------------
// LDS per stream (halfs): q@0, q2@2048, k@4096, Pb-extra@6144, vt@8192 -> 10240h (20KB)
// Pa aliases q+q2 (@0..4095), Pb aliases k+extra (@4096..8191). 40KB total, 3 barriers.
__global__ void __launch_bounds__(256, 4) attn_kernel(
    const unsigned short* __restrict__ xg,
    const unsigned short* __restrict__ Wqkv, const float* __restrict__ bqkv,
    const float* __restrict__ biasmat,
    unsigned short* __restrict__ aout)
{
  __shared__ unsigned short smem[2][10240];

  const int tid = threadIdx.x, wid = tid >> 6, lane = tid & 63;
  const int l4 = lane >> 4, l15 = lane & 15;
  const int win = blockIdx.x >> 2, h = blockIdx.x & 3;
  const f32x4 fzero = {0.f, 0.f, 0.f, 0.f};

  // ---- A-fragments straight from pre-LN'd bf16 ----
  bf16x8 aF[2][4];
#pragma unroll
  for (int s = 0; s < 2; ++s) {
    const unsigned short* Ax = xg + ((size_t)s * 65536 + (size_t)win * 64 + wid * 16 + l15) * 128 + l4 * 8;
#pragma unroll
    for (int kk = 0; kk < 4; ++kk) aF[s][kk] = *(const bf16x8*)(Ax + kk * 32);
  }

  // ---- QKV: M=16/wave per stream, N=128 (4 comps x 32), K=128 ----
  {
    f32x4 acc[2][8];
#pragma unroll
    for (int s = 0; s < 2; ++s)
#pragma unroll
      for (int n = 0; n < 8; ++n) acc[s][n] = fzero;
#pragma unroll
    for (int kk = 0; kk < 4; ++kk)
#pragma unroll
      for (int nf = 0; nf < 8; ++nf) {
        const int comp = nf >> 1, sub = (nf & 1) * 16 + l15;
        bf16x8 bb = *(const bf16x8*)(Wqkv + (comp * 128 + h * 32 + sub) * 128 + kk * 32 + l4 * 8);
        acc[0][nf] = __builtin_amdgcn_mfma_f32_16x16x32_bf16(aF[0][kk], bb, acc[0][nf], 0, 0, 0);
        acc[1][nf] = __builtin_amdgcn_mfma_f32_16x16x32_bf16(aF[1][kk], bb, acc[1][nf], 0, 0, 0);
      }
    float bv[8];
#pragma unroll
    for (int nf = 0; nf < 8; ++nf) bv[nf] = bqkv[(nf >> 1) * 128 + h * 32 + (nf & 1) * 16 + l15];
#pragma unroll
    for (int s = 0; s < 2; ++s)
#pragma unroll
      for (int r = 0; r < 4; ++r) {
        const int tw = wid * 16 + l4 * 4 + r;
        // q / k / q2: pi1-packed b32 stores ([64][32h] tiles, mask 3)
        ldst32(smem[s] + 0,    tw, 32, 2 * l15, 3, pk2(acc[s][0][r] + bv[0], acc[s][1][r] + bv[1]));
        ldst32(smem[s] + 4096, tw, 32, 2 * l15, 3, pk2(acc[s][2][r] + bv[2], acc[s][3][r] + bv[3]));
        ldst32(smem[s] + 2048, tw, 32, 2 * l15, 3, pk2(acc[s][6][r] + bv[6], acc[s][7][r] + bv[7]));
        // vt [32 hd][64 tok], token column in pi3 order: pi3(tw) = 16*l4 + 4*r + wid
        const int vc = 16 * l4 + 4 * r + wid;
        ldss(smem[s] + 8192, l15,      64, vc, 7, f2bf(acc[s][4][r] + bv[4]));
        ldss(smem[s] + 8192, 16 + l15, 64, vc, 7, f2bf(acc[s][5][r] + bv[5]));
      }
  }
  __syncthreads();

  // ---- scores: wave -> (stream s, kind). Read operands to regs, then sync (alias safety). ----
  const int s = wid >> 1, kind = wid & 1;
  bf16x8 aR[4], kR[4];
  {
    const unsigned short* Ab = kind ? (smem[1 - s] + 2048) : (smem[s] + 0);
    const unsigned short* Kb = smem[s] + 4096;
#pragma unroll
    for (int mf = 0; mf < 4; ++mf) aR[mf] = ldsv(Ab, mf * 16 + l15, 32, l4 * 8, 3);
#pragma unroll
    for (int nf = 0; nf < 4; ++nf) kR[nf] = ldsv(Kb, nf * 16 + l15, 32, l4 * 8, 3);
  }
  __syncthreads();

  f32x4 sc[4][4];
#pragma unroll
  for (int mf = 0; mf < 4; ++mf)
#pragma unroll
    for (int nf = 0; nf < 4; ++nf) sc[mf][nf] = fzero;
#pragma unroll
  for (int mf = 0; mf < 4; ++mf)
#pragma unroll
    for (int nf = 0; nf < 4; ++nf)
      sc[mf][nf] = __builtin_amdgcn_mfma_f32_16x16x32_bf16(aR[mf], kR[nf], sc[mf][nf], 0, 0, 0);

  if (s == 0 && kind == 0) {  // rel-pos bias only on the r-branch
#pragma unroll
    for (int mf = 0; mf < 4; ++mf)
#pragma unroll
      for (int nf = 0; nf < 4; ++nf)
#pragma unroll
        for (int r = 0; r < 4; ++r) {
          int row = mf * 16 + l4 * 4 + r, col = nf * 16 + l15;
          sc[mf][nf][r] += biasmat[(h * 64 + row) * 64 + col];
        }
  }
  // in-register softmax per row
#pragma unroll
  for (int mf = 0; mf < 4; ++mf)
#pragma unroll
    for (int r = 0; r < 4; ++r) {
      float v0 = sc[mf][0][r], v1 = sc[mf][1][r], v2 = sc[mf][2][r], v3 = sc[mf][3][r];
      float m = fmaxf(fmaxf(v0, v1), fmaxf(v2, v3));
      m = fmaxf(m, __shfl_xor(m, 1));
      m = fmaxf(m, __shfl_xor(m, 2));
      m = fmaxf(m, __shfl_xor(m, 4));
      m = fmaxf(m, __shfl_xor(m, 8));
      float e0 = __expf(v0 - m), e1 = __expf(v1 - m), e2 = __expf(v2 - m), e3 = __expf(v3 - m);
      float sm = e0 + e1 + e2 + e3;
      sm += __shfl_xor(sm, 1); sm += __shfl_xor(sm, 2);
      sm += __shfl_xor(sm, 4); sm += __shfl_xor(sm, 8);
      float inv = 1.f / sm;
      sc[mf][0][r] = e0 * inv; sc[mf][1][r] = e1 * inv;
      sc[mf][2][r] = e2 * inv; sc[mf][3][r] = e3 * inv;
    }
  // write Pa (kind0) / Pb (kind1), columns in pi3 order: col' = 4*l15 + nf, b64 packed
  {
    unsigned short* Ptgt = smem[s] + (kind ? 4096 : 0);
#pragma unroll
    for (int mf = 0; mf < 4; ++mf)
#pragma unroll
      for (int r = 0; r < 4; ++r)
        ldst64(Ptgt, mf * 16 + l4 * 4 + r, 64, 4 * l15, 7,
               pk2(sc[mf][0][r], sc[mf][1][r]), pk2(sc[mf][2][r], sc[mf][3][r]));
  }
  __syncthreads();

  // ---- PV: wave handles rows kind*32..+32; K=128 over Pa then Pb ----
  {
    const unsigned short* Vt = smem[s] + 8192;
    bf16x8 vR[2][2];
#pragma unroll
    for (int kk = 0; kk < 2; ++kk)
#pragma unroll
      for (int nf = 0; nf < 2; ++nf) vR[kk][nf] = ldsv(Vt, nf * 16 + l15, 64, kk * 32 + l4 * 8, 7);
    f32x4 pv[2][2];
    pv[0][0] = fzero; pv[0][1] = fzero; pv[1][0] = fzero; pv[1][1] = fzero;
#pragma unroll
    for (int pb_i = 0; pb_i < 2; ++pb_i) {
      const unsigned short* Pbuf = smem[s] + pb_i * 4096;
#pragma unroll
      for (int kk = 0; kk < 2; ++kk) {
        bf16x8 pa0 = ldsv(Pbuf, kind * 32 + l15, 64, kk * 32 + l4 * 8, 7);
        bf16x8 pa1 = ldsv(Pbuf, kind * 32 + 16 + l15, 64, kk * 32 + l4 * 8, 7);
#pragma unroll
        for (int nf = 0; nf < 2; ++nf) {
          pv[0][nf] = __builtin_amdgcn_mfma_f32_16x16x32_bf16(pa0, vR[kk][nf], pv[0][nf], 0, 0, 0);
          pv[1][nf] = __builtin_amdgcn_mfma_f32_16x16x32_bf16(pa1, vR[kk][nf], pv[1][nf], 0, 0, 0);
        }
      }
    }
    // aout channels in pi1 order within this head's 32-chunk: c' = h*32 + 2*l15 + nf
#pragma unroll
    for (int mf = 0; mf < 2; ++mf)
#pragma unroll
      for (int r = 0; r < 4; ++r) {
        int tw = kind * 32 + mf * 16 + l4 * 4 + r;
        *(unsigned int*)(aout + ((size_t)s * 65536 + (size_t)win * 64 + tw) * 128 + h * 32 + 2 * l15) =
            pk2(pv[mf][0][r], pv[mf][1][r]);
      }
  }
}

// ---------------- proj GEMM + residual + window-reverse + fused LN2 -> xn2 ----------------
__global__ void __launch_bounds__(256, 4) proj_kernel(
    const unsigned short* __restrict__ aout, const unsigned short* __restrict__ Wprojs,
    const float* __restrict__ projb,
    const float* __restrict__ x_in, const float* __restrict__ d_in_,
    const float* __restrict__ n2w, const float* __restrict__ n2b,
    float* __restrict__ out, unsigned short* __restrict__ xn2)
{
  const int tid = threadIdx.x, wid = tid >> 6, lane = tid & 63;
  const int l4 = lane >> 4, l15 = lane & 15;
  const int s = blockIdx.x >> 9, blk = blockIdx.x & 511;
  const int row0 = blk * 128 + wid * 32;
  const unsigned short* A = aout + (size_t)s * 65536 * 128;
  const f32x4 fzero = {0.f, 0.f, 0.f, 0.f};

  bf16x8 aF[2][4];
#pragma unroll
  for (int mf = 0; mf < 2; ++mf)
#pragma unroll
    for (int kk = 0; kk < 4; ++kk)
      aF[mf][kk] = *(const bf16x8*)(A + (size_t)(row0 + mf * 16 + l15) * 128 + kk * 32 + l4 * 8);

  f32x4 acc[2][8];
#pragma unroll
  for (int mf = 0; mf < 2; ++mf)
#pragma unroll
    for (int nf = 0; nf < 8; ++nf) acc[mf][nf] = fzero;
#pragma unroll
  for (int kk = 0; kk < 4; ++kk)
#pragma unroll
    for (int nf = 0; nf < 8; ++nf) {
      bf16x8 bb = *(const bf16x8*)(Wprojs + (nf * 16 + l15) * 128 + kk * 32 + l4 * 8);
      acc[0][nf] = __builtin_amdgcn_mfma_f32_16x16x32_bf16(aF[0][kk], bb, acc[0][nf], 0, 0, 0);
      acc[1][nf] = __builtin_amdgcn_mfma_f32_16x16x32_bf16(aF[1][kk], bb, acc[1][nf], 0, 0, 0);
    }

  float pbv[8], w2v[8], b2v[8];
#pragma unroll
  for (int nf = 0; nf < 8; ++nf) {
    int col = nf * 16 + l15;
    pbv[nf] = projb[col]; w2v[nf] = n2w[col]; b2v[nf] = n2b[col];
  }
  const float* resid = s ? d_in_ : x_in;
  float* dst = out + (size_t)s * 8388608;
#pragma unroll
  for (int mf = 0; mf < 2; ++mf)
#pragma unroll
    for (int r = 0; r < 4; ++r) {
      int t = row0 + mf * 16 + l4 * 4 + r;
      int w2 = t >> 6, tk = t & 63;
      int b2 = w2 >> 8, hb = (w2 >> 4) & 15, wb = w2 & 15;
      int grow = b2 * 16384 + hb * 1024 + (tk >> 3) * 128 + wb * 8 + (tk & 7);
      float v[8];
      float sum = 0.f, ssq = 0.f;
#pragma unroll
      for (int nf = 0; nf < 8; ++nf) {
        size_t off = (size_t)grow * 128 + nf * 16 + l15;
        float val = acc[mf][nf][r] + pbv[nf] + resid[off];
        v[nf] = val; sum += val; ssq += val * val;
        dst[off] = val;
      }
      sum += __shfl_xor(sum, 1); sum += __shfl_xor(sum, 2);
      sum += __shfl_xor(sum, 4); sum += __shfl_xor(sum, 8);
      ssq += __shfl_xor(ssq, 1); ssq += __shfl_xor(ssq, 2);
      ssq += __shfl_xor(ssq, 4); ssq += __shfl_xor(ssq, 8);
      float mean = sum * (1.f / 128.f);
      float var = ssq * (1.f / 128.f) - mean * mean;
      float rs = rsqrtf(var + 1e-5f);
      float g[8];
#pragma unroll
      for (int nf = 0; nf < 8; ++nf) g[nf] = (v[nf] - mean) * rs * w2v[nf] + b2v[nf];
      // xn2 in pi layout: c' = 8*l15 + nf -> one b128 store
      *(bf16x8*)(xn2 + ((size_t)(s * 65536 + grow)) * 128 + l15 * 8) = pack8(g);
    }
}

// ---------------- MLP: fc1(gelu)+fc2, A from pre-LN'd xn2; 1 block = 32 tokens ----------------
__global__ void __launch_bounds__(256, 4) mlp_kernel(
    const unsigned short* __restrict__ xn2,
    const unsigned short* __restrict__ Wfc1s, const float* __restrict__ fc1b,
    const unsigned short* __restrict__ Wfc2s, const float* __restrict__ fc2b,
    float* __restrict__ out)
{
  __shared__ unsigned short hbuf[32 * 512];  // 32KB (mask 7), columns in pi order
  const int tid = threadIdx.x, wid = tid >> 6, lane = tid & 63;
  const int l4 = lane >> 4, l15 = lane & 15;
  const size_t rbase = (size_t)blockIdx.x * 32;
  const f32x4 fzero = {0.f, 0.f, 0.f, 0.f};

  // fc1 + gelu: wave w owns N chunk w*128..+128; A straight from global (pi-k layout)
  {
    bf16x8 aF[2][4];
#pragma unroll
    for (int mf = 0; mf < 2; ++mf)
#pragma unroll
      for (int kk = 0; kk < 4; ++kk)
        aF[mf][kk] = *(const bf16x8*)(xn2 + (rbase + mf * 16 + l15) * 128 + kk * 32 + l4 * 8);
    f32x4 acc[2][8];
#pragma unroll
    for (int mf = 0; mf < 2; ++mf)
#pragma unroll
      for (int nf = 0; nf < 8; ++nf) acc[mf][nf] = fzero;
#pragma unroll
    for (int kk = 0; kk < 4; ++kk)
#pragma unroll
      for (int nf = 0; nf < 8; ++nf) {
        int n = wid * 128 + nf * 16 + l15;
        bf16x8 bb = *(const bf16x8*)(Wfc1s + (size_t)n * 128 + kk * 32 + l4 * 8);
        acc[0][nf] = __builtin_amdgcn_mfma_f32_16x16x32_bf16(aF[0][kk], bb, acc[0][nf], 0, 0, 0);
        acc[1][nf] = __builtin_amdgcn_mfma_f32_16x16x32_bf16(aF[1][kk], bb, acc[1][nf], 0, 0, 0);
      }
    float b1v[8];
#pragma unroll
    for (int nf = 0; nf < 8; ++nf) b1v[nf] = fc1b[wid * 128 + nf * 16 + l15];
#pragma unroll
    for (int mf = 0; mf < 2; ++mf)
#pragma unroll
      for (int r = 0; r < 4; ++r) {
        float g[8];
#pragma unroll
        for (int nf = 0; nf < 8; ++nf) {
          float vv = acc[mf][nf][r] + b1v[nf];
          // gelu via tanh form (|u|-safe): max |err| vs exact erf ~3e-3
          float u = vv * (0.7978845608028654f + 0.035677408136300125f * vv * vv);
          float au = fabsf(u);
          float e = __expf(-2.f * au);
          float th = (1.f - e) / (1.f + e);
          th = copysignf(th, u);
          g[nf] = 0.5f * vv * (1.f + th);
        }
        // hbuf col' = wid*128 + 8*l15 + nf -> one b128 store
        ldst128(hbuf, mf * 16 + l4 * 4 + r, 512, wid * 128 + l15 * 8, 7, pack8(g));
      }
  }
  __syncthreads();
  // fc2 + residual: wave w owns N chunk w*32..+32, K=512 (pi-consistent with Wfc2s)
  {
    f32x4 a2[2][2];
    a2[0][0] = fzero; a2[0][1] = fzero; a2[1][0] = fzero; a2[1][1] = fzero;
#pragma unroll
    for (int kk = 0; kk < 16; ++kk) {
      bf16x8 h0 = ldsv(hbuf, l15, 512, kk * 32 + l4 * 8, 7);
      bf16x8 h1 = ldsv(hbuf, 16 + l15, 512, kk * 32 + l4 * 8, 7);
#pragma unroll
      for (int nf = 0; nf < 2; ++nf) {
        int n = wid * 32 + nf * 16 + l15;
        bf16x8 bb = *(const bf16x8*)(Wfc2s + (size_t)n * 512 + kk * 32 + l4 * 8);
        a2[0][nf] = __builtin_amdgcn_mfma_f32_16x16x32_bf16(h0, bb, a2[0][nf], 0, 0, 0);
        a2[1][nf] = __builtin_amdgcn_mfma_f32_16x16x32_bf16(h1, bb, a2[1][nf], 0, 0, 0);
      }
    }
#pragma unroll
    for (int mf = 0; mf < 2; ++mf)
#pragma unroll
      for (int nf = 0; nf < 2; ++nf) {
        int col = wid * 32 + nf * 16 + l15;
        float bias = fc2b[col];
#pragma unroll
        for (int r = 0; r < 4; ++r) {
          int row = mf * 16 + l4 * 4 + r;
          size_t off = (rbase + row) * 128 + col;
          out[off] = a2[mf][nf][r] + bias + out[off];
        }
      }
  }
}

extern "C" void kernel_launch(void* const* d_in, const int* in_sizes, int n_in,
                              void* d_out, int out_size, void* d_ws, size_t ws_size,
                              hipStream_t stream) {
  const float* x    = (const float*)d_in[0];
  const float* dd   = (const float*)d_in[1];
  const float* rpb  = (const float*)d_in[2];
  const float* n1w  = (const float*)d_in[3];
  const float* n1b  = (const float*)d_in[4];
  const float* n2w  = (const float*)d_in[5];
  const float* n2b  = (const float*)d_in[6];
  const float* qkvw = (const float*)d_in[7];
  const float* qkvb = (const float*)d_in[8];
  const float* pw   = (const float*)d_in[9];
  const float* pb   = (const float*)d_in[10];
  const float* f1w  = (const float*)d_in[11];
  const float* f1b  = (const float*)d_in[12];
  const float* f2w  = (const float*)d_in[13];
  const float* f2b  = (const float*)d_in[14];
  float* out = (float*)d_out;
  char* ws = (char*)d_ws;
  unsigned short* Wqkv   = (unsigned short*)(ws);
  unsigned short* Wprojs = (unsigned short*)(ws + 131072);
  unsigned short* Wfc1s  = (unsigned short*)(ws + 163840);
  unsigned short* Wfc2s  = (unsigned short*)(ws + 294912);
  float* bqkv            = (float*)(ws + 425984);
  float* biasmat         = (float*)(ws + 428032);
  unsigned short* aout   = (unsigned short*)(ws + 524288);             // 33.5MB
  unsigned short* xn2    = (unsigned short*)(ws + 524288 + 33554432);  // 33.5MB
  // LN1 output staged in d_out (read by attn before proj overwrites it)
  unsigned short* xg     = (unsigned short*)d_out;

  prep_kernel<<<dim3(899), dim3(256), 0, stream>>>(qkvw, qkvb, pw, f1w, f2w, rpb,
                                                   Wqkv, Wprojs, Wfc1s, Wfc2s, bqkv, biasmat);
  ln1_kernel<<<dim3(2048), dim3(256), 0, stream>>>(x, dd, n1w, n1b, xg);
  attn_kernel<<<dim3(4096), dim3(256), 0, stream>>>(xg, Wqkv, bqkv, biasmat, aout);
  proj_kernel<<<dim3(1024), dim3(256), 0, stream>>>(aout, Wprojs, pb, x, dd, n2w, n2b, out, xn2);
  mlp_kernel<<<dim3(4096), dim3(256), 0, stream>>>(xn2, Wfc1s, f1b, Wfc2s, f2b, out);
}